// Round 3
// baseline (19156.578 us; speedup 1.0000x reference)
//
#include <hip/hip_runtime.h>
#include <cstdint>
#include <cstddef>

// ---------------- constants ----------------
#define BB 512
#define HH 64
#define WW 64
#define TT 32
#define LL 1024
#define ZZ 128
#define NN 12   // RS == WS == 12

// ---------------- math helpers ----------------
__device__ __forceinline__ float sigf(float x) { return 1.0f / (1.0f + expf(-x)); }

// XLA ErfInv32 (Giles polynomial), as used by jax.random.normal (f32)
__device__ __forceinline__ float jax_erfinv(float x) {
  float w = -log1pf(-x * x);
  float p;
  if (w < 5.0f) {
    w = w - 2.5f;
    p = 2.81022636e-08f;
    p = fmaf(p, w, 3.43273939e-07f);
    p = fmaf(p, w, -3.5233877e-06f);
    p = fmaf(p, w, -4.39150654e-06f);
    p = fmaf(p, w, 0.00021858087f);
    p = fmaf(p, w, -0.00125372503f);
    p = fmaf(p, w, -0.00417768164f);
    p = fmaf(p, w, 0.246640727f);
    p = fmaf(p, w, 1.50140941f);
  } else {
    w = sqrtf(w) - 3.0f;
    p = -0.000200214257f;
    p = fmaf(p, w, 0.000100950558f);
    p = fmaf(p, w, 0.00134934322f);
    p = fmaf(p, w, -0.00367342844f);
    p = fmaf(p, w, 0.00573950773f);
    p = fmaf(p, w, -0.0076224613f);
    p = fmaf(p, w, 0.00943887047f);
    p = fmaf(p, w, 1.00167406f);
    p = fmaf(p, w, 2.83297682f);
  }
  return p * x;
}

// Threefry-2x32, 20 rounds, exactly JAX's schedule
__device__ __forceinline__ void threefry(uint32_t k0, uint32_t k1,
                                         uint32_t x0, uint32_t x1,
                                         uint32_t& o0, uint32_t& o1) {
  uint32_t ks0 = k0, ks1 = k1, ks2 = k0 ^ k1 ^ 0x1BD11BDAu;
  x0 += ks0; x1 += ks1;
#define TF_ROT(x, d) (((x) << (d)) | ((x) >> (32 - (d))))
#define TF_RND(r) { x0 += x1; x1 = TF_ROT(x1, r); x1 ^= x0; }
  TF_RND(13) TF_RND(15) TF_RND(26) TF_RND(6)
  x0 += ks1; x1 += ks2 + 1u;
  TF_RND(17) TF_RND(29) TF_RND(16) TF_RND(24)
  x0 += ks2; x1 += ks0 + 2u;
  TF_RND(13) TF_RND(15) TF_RND(26) TF_RND(6)
  x0 += ks0; x1 += ks1 + 3u;
  TF_RND(17) TF_RND(29) TF_RND(16) TF_RND(24)
  x0 += ks1; x1 += ks2 + 4u;
  TF_RND(13) TF_RND(15) TF_RND(26) TF_RND(6)
  x0 += ks2; x1 += ks0 + 5u;
#undef TF_RND
#undef TF_ROT
  o0 = x0; o1 = x1;
}

// bits -> uniform(-0.99999994, 1.0) -> sqrt(2)*erfinv  (matches jax.random.normal f32)
__device__ __forceinline__ float bits_to_normal(uint32_t bits) {
  uint32_t fb = (bits >> 9) | 0x3f800000u;
  float f = __uint_as_float(fb) - 1.0f;      // [0,1)
  const float lo = -0.99999994f;             // nextafter(-1,0)
  float u = fmaxf(lo, f * 2.0f + lo);        // hi-lo rounds to exactly 2.0f
  return 1.41421356237f * jax_erfinv(u);
}

// ---------------- RNG kernels (jax_threefry_partitionable=True scheme) ----------------
// split(key(42), 32): key_t = threefry((0,42), x0=hi=0, x1=lo=t) -> (o0, o1)
__global__ void k_keys(uint32_t* __restrict__ keys) {
  int t = threadIdx.x;
  if (t >= TT) return;
  uint32_t a, b;
  threefry(0u, 42u, 0u, (uint32_t)t, a, b);
  keys[2 * t] = a;
  keys[2 * t + 1] = b;
}

// random_bits(key_t, 32, (512,128)): bits[i] = o0 ^ o1 of threefry(key_t, 0, i)
__global__ __launch_bounds__(256) void k_rng(const uint32_t* __restrict__ keys,
                                             float* __restrict__ eps) {
  int t = blockIdx.y;
  int i = blockIdx.x * 256 + threadIdx.x;  // < 65536
  uint32_t o0, o1;
  threefry(keys[2 * t], keys[2 * t + 1], 0u, (uint32_t)i, o0, o1);
  eps[(size_t)t * 65536 + i] = bits_to_normal(o0 ^ o1);
}

// ---------------- GEMM: C[M,N] = sum_s A_s[M,Ks] @ W_s[N,Ks]^T + b0 + b1 ----------------
__global__ __launch_bounds__(256) void gemm3_kernel(
    float* __restrict__ C, int M, int N,
    const float* __restrict__ A0, const float* __restrict__ W0, int K0, int lda0, int ldw0,
    const float* __restrict__ A1, const float* __restrict__ W1, int K1, int lda1, int ldw1,
    const float* __restrict__ A2, const float* __restrict__ W2, int K2, int lda2, int ldw2,
    const float* __restrict__ b0, const float* __restrict__ b1) {
  __shared__ float As[16][68];
  __shared__ float Bs[16][68];
  const int bm = blockIdx.y * 64, bn = blockIdx.x * 64;
  const int tid = threadIdx.x, tx = tid & 15, ty = tid >> 4;
  float acc[4][4] = {{0.f}};

  const float* Aarr[3] = {A0, A1, A2};
  const float* Warr[3] = {W0, W1, W2};
  const int Karr[3] = {K0, K1, K2};
  const int ldaA[3] = {lda0, lda1, lda2};
  const int ldwA[3] = {ldw0, ldw1, ldw2};

#pragma unroll
  for (int s = 0; s < 3; ++s) {
    const float* A = Aarr[s];
    const float* W = Warr[s];
    const int K = Karr[s], lda = ldaA[s], ldw = ldwA[s];
    if (K == 0) continue;
    for (int k0 = 0; k0 < K; k0 += 16) {
#pragma unroll
      for (int i = 0; i < 4; ++i) {
        int e = tid + 256 * i;
        int row = e >> 4, kk = e & 15;
        As[kk][row] = A[(size_t)(bm + row) * lda + k0 + kk];
        int n = bn + row;
        Bs[kk][row] = (n < N) ? W[(size_t)n * ldw + k0 + kk] : 0.f;
      }
      __syncthreads();
#pragma unroll
      for (int kk = 0; kk < 16; ++kk) {
        float4 av = *reinterpret_cast<const float4*>(&As[kk][ty * 4]);
        float4 bv = *reinterpret_cast<const float4*>(&Bs[kk][tx * 4]);
        const float a4[4] = {av.x, av.y, av.z, av.w};
        const float b4[4] = {bv.x, bv.y, bv.z, bv.w};
#pragma unroll
        for (int i = 0; i < 4; ++i)
#pragma unroll
          for (int j = 0; j < 4; ++j) acc[i][j] = fmaf(a4[i], b4[j], acc[i][j]);
      }
      __syncthreads();
    }
  }
#pragma unroll
  for (int i = 0; i < 4; ++i) {
    int m = bm + ty * 4 + i;
#pragma unroll
    for (int j = 0; j < 4; ++j) {
      int n = bn + tx * 4 + j;
      if (n < N) {
        float v = acc[i][j];
        if (b0) v += b0[n];
        if (b1) v += b1[n];
        C[(size_t)m * N + n] = v;
      }
    }
  }
}

// ---------------- attention params + filterbank ----------------
template <int WRITE>
__global__ __launch_bounds__(256) void k_attn(
    const float* __restrict__ h_dec, const float* __restrict__ aW, const float* __restrict__ ab,
    float* __restrict__ Fx, float* __restrict__ Fy, float* __restrict__ gamma) {
  int b = blockIdx.x;
  __shared__ float a_sh[5];
  __shared__ float fx_sh[12][64], fy_sh[12][64];
  __shared__ float srow[24];
  int tid = threadIdx.x;
  int wave = tid >> 6, lane = tid & 63;
  const float* h = h_dec + (size_t)b * LL;
  for (int o = wave; o < 5; o += 4) {
    float s = 0.f;
    const float* w = aW + (size_t)o * LL;
    for (int k = lane; k < LL; k += 64) s += h[k] * w[k];
#pragma unroll
    for (int d = 32; d; d >>= 1) s += __shfl_xor(s, d, 64);
    if (lane == 0) a_sh[o] = s + ab[o];
  }
  __syncthreads();
  float gx = 32.5f * (a_sh[0] + 1.f);            // 0.5*(W+1)*(gx+1)
  float gy = 32.5f * (a_sh[1] + 1.f);
  float i2v = 0.5f * expf(-a_sh[2]);             // 0.5/exp(logvar)
  float delta = (63.f / 11.f) * expf(a_sh[3]);   // (max(H,W)-1)/(N-1)*exp(logdelta)
  if (tid == 0) gamma[b] = WRITE ? expf(-a_sh[4]) : expf(a_sh[4]);
  for (int e = tid; e < 768; e += 256) {
    int n = e >> 6, p = e & 63;
    float mu_x = gx + ((float)n - 5.5f) * delta;
    float mu_y = gy + ((float)n - 5.5f) * delta;
    float dx = (float)(p + 1) - mu_x;
    float dy = (float)(p + 1) - mu_y;
    fx_sh[n][p] = expf(-i2v * dx * dx);
    fy_sh[n][p] = expf(-i2v * dy * dy);
  }
  __syncthreads();
  if (tid < 24) {
    int n = tid % 12;
    float s = 0.f;
    if (tid < 12) { for (int p = 0; p < 64; ++p) s += fx_sh[n][p]; }
    else          { for (int p = 0; p < 64; ++p) s += fy_sh[n][p]; }
    srow[tid] = s + 6.4e-7f;  // sum(F + 1e-8) = sum(F) + 64*1e-8
  }
  __syncthreads();
  for (int e = tid; e < 768; e += 256) {
    int n = e >> 6, p = e & 63;
    Fx[((size_t)b * 12 + n) * 64 + p] = fx_sh[n][p] / srow[n];
    Fy[((size_t)b * 12 + n) * 64 + p] = fy_sh[n][p] / srow[12 + n];
  }
}

// ---------------- read: r = gamma * [Fy X Fx^T , Fy Xhat Fx^T] ----------------
__global__ __launch_bounds__(256) void k_read(
    const float* __restrict__ x, const float* __restrict__ c,
    const float* __restrict__ Fx, const float* __restrict__ Fy,
    const float* __restrict__ gamma, float* __restrict__ r) {
  int b = blockIdx.x;
  __shared__ float X[64][64];
  __shared__ float Xh[64][64];
  __shared__ float fx[12][64], fy[12][64];
  __shared__ float tmp[12][64], tmph[12][64];
  int tid = threadIdx.x;
  for (int e = tid; e < 4096; e += 256) {
    float xv = x[(size_t)b * 4096 + e];
    float cv = c[(size_t)b * 4096 + e];
    X[e >> 6][e & 63] = xv;
    Xh[e >> 6][e & 63] = xv - sigf(cv);   // x_hat = x - sigmoid(c)
  }
  for (int e = tid; e < 768; e += 256) {
    fx[e >> 6][e & 63] = Fx[(size_t)b * 768 + e];
    fy[e >> 6][e & 63] = Fy[(size_t)b * 768 + e];
  }
  __syncthreads();
  for (int e = tid; e < 768; e += 256) {
    int n = e >> 6, w2 = e & 63;
    float s = 0.f, sh = 0.f;
    for (int hh = 0; hh < 64; ++hh) {
      float f = fy[n][hh];
      s  = fmaf(f, X[hh][w2], s);
      sh = fmaf(f, Xh[hh][w2], sh);
    }
    tmp[n][w2] = s; tmph[n][w2] = sh;
  }
  __syncthreads();
  float gam = gamma[b];
  if (tid < 144) {
    int n = tid / 12, m = tid % 12;
    float s = 0.f, sh = 0.f;
    for (int w2 = 0; w2 < 64; ++w2) {
      float f = fx[m][w2];
      s  = fmaf(tmp[n][w2], f, s);
      sh = fmaf(tmph[n][w2], f, sh);
    }
    r[(size_t)b * 288 + n * 12 + m] = gam * s;
    r[(size_t)b * 288 + 144 + n * 12 + m] = gam * sh;
  }
}

// ---------------- write: c += gamma * Fy^T w Fx ----------------
__global__ __launch_bounds__(256) void k_write(
    float* __restrict__ c, const float* __restrict__ wvec,
    const float* __restrict__ Fx, const float* __restrict__ Fy,
    const float* __restrict__ gamma) {
  int b = blockIdx.x;
  __shared__ float fx[12][64], fy[12][64], wsm[12][12], tmp[12][64];
  int tid = threadIdx.x;
  for (int e = tid; e < 768; e += 256) {
    fx[e >> 6][e & 63] = Fx[(size_t)b * 768 + e];
    fy[e >> 6][e & 63] = Fy[(size_t)b * 768 + e];
  }
  if (tid < 144) wsm[tid / 12][tid % 12] = wvec[(size_t)b * 144 + tid];
  __syncthreads();
  for (int e = tid; e < 768; e += 256) {
    int n = e >> 6, w2 = e & 63;
    float s = 0.f;
#pragma unroll
    for (int m = 0; m < 12; ++m) s = fmaf(wsm[n][m], fx[m][w2], s);
    tmp[n][w2] = s;
  }
  __syncthreads();
  float gam = gamma[b];
  for (int e = tid; e < 4096; e += 256) {
    int hh = e >> 6, w2 = e & 63;
    float s = 0.f;
#pragma unroll
    for (int n = 0; n < 12; ++n) s = fmaf(fy[n][hh], tmp[n][w2], s);
    c[(size_t)b * 4096 + e] += gam * s;
  }
}

// ---------------- LSTM gates ----------------
__global__ __launch_bounds__(256) void k_lstm(const float* __restrict__ g,
                                              float* __restrict__ h, float* __restrict__ cst) {
  int i = blockIdx.x * 256 + threadIdx.x;  // < 512*1024
  int b = i >> 10, u = i & 1023;
  const float* gb = g + (size_t)b * 4096;
  float ig = gb[u], fg = gb[1024 + u], gg = gb[2048 + u], og = gb[3072 + u];
  float cv = sigf(fg) * cst[i] + sigf(ig) * tanhf(gg);
  cst[i] = cv;
  h[i] = sigf(og) * tanhf(cv);
}

// ---------------- z = mu + sig*eps; write mus/sigs outputs ----------------
__global__ __launch_bounds__(256) void k_z(const float* __restrict__ stats,
                                           const float* __restrict__ eps_t,
                                           float* __restrict__ z,
                                           float* __restrict__ out_mu,
                                           float* __restrict__ out_sg, int t) {
  int i = blockIdx.x * 256 + threadIdx.x;  // < 65536
  int b = i >> 7, zi = i & 127;
  float mu = stats[(size_t)b * 256 + zi];
  float sg = expf(stats[(size_t)b * 256 + 128 + zi]);
  z[i] = mu + sg * eps_t[i];
  out_mu[(size_t)b * 4096 + zi * 32 + t] = mu;  // (B, Z, T) layout
  out_sg[(size_t)b * 4096 + zi * 32 + t] = sg;
}

// ---------------- host launch ----------------
extern "C" void kernel_launch(void* const* d_in, const int* in_sizes, int n_in,
                              void* d_out, int out_size, void* d_ws, size_t ws_size,
                              hipStream_t stream) {
  const float* x       = (const float*)d_in[0];
  const float* enc_Wih = (const float*)d_in[1];
  const float* enc_Whh = (const float*)d_in[2];
  const float* enc_bih = (const float*)d_in[3];
  const float* enc_bhh = (const float*)d_in[4];
  const float* dec_Wih = (const float*)d_in[5];
  const float* dec_Whh = (const float*)d_in[6];
  const float* dec_bih = (const float*)d_in[7];
  const float* dec_bhh = (const float*)d_in[8];
  const float* zW  = (const float*)d_in[9];
  const float* zb  = (const float*)d_in[10];
  const float* wW  = (const float*)d_in[11];
  const float* wb  = (const float*)d_in[12];
  const float* raW = (const float*)d_in[13];
  const float* rab = (const float*)d_in[14];
  const float* waW = (const float*)d_in[15];
  const float* wab = (const float*)d_in[16];

  float* out = (float*)d_out;
  float* c      = out;                // (512, 4096) canvas lives in d_out
  float* out_mu = out + 2097152;
  float* out_sg = out + 4194304;

  float* ws = (float*)d_ws;
  float* h_enc = ws + 0;
  float* c_enc = ws + 524288;
  float* h_dec = ws + 1048576;
  float* c_dec = ws + 1572864;
  float* eps   = ws + 2097152;   // 32*512*128
  float* gbuf  = ws + 4194304;   // 512*4096 (shared enc/dec gates)
  float* rbuf  = ws + 6291456;   // 512*288
  float* stats = ws + 6438912;   // 512*256
  float* zbuf  = ws + 6569984;   // 512*128
  float* Fx    = ws + 6635520;   // 512*12*64
  float* Fy    = ws + 7028736;
  float* gam   = ws + 7421952;   // 512
  float* wvec  = ws + 7422464;   // 512*144
  uint32_t* keys = (uint32_t*)(ws + 7496192);  // 64 u32

  // zero canvas + recurrent states (harness poisons once, never re-poisons)
  hipMemsetAsync(c, 0, (size_t)2097152 * sizeof(float), stream);
  hipMemsetAsync(ws, 0, (size_t)4 * 524288 * sizeof(float), stream);

  k_keys<<<1, 64, 0, stream>>>(keys);
  k_rng<<<dim3(256, 32), 256, 0, stream>>>(keys, eps);

  for (int t = 0; t < TT; ++t) {
    // read attention (uses previous h_dec)
    k_attn<0><<<512, 256, 0, stream>>>(h_dec, raW, rab, Fx, Fy, gam);
    k_read<<<512, 256, 0, stream>>>(x, c, Fx, Fy, gam, rbuf);
    // enc LSTM: g = [r | h_dec] @ Wih^T + h_enc @ Whh^T + bih + bhh
    gemm3_kernel<<<dim3(64, 8), 256, 0, stream>>>(gbuf, 512, 4096,
        rbuf,  enc_Wih,        288, 288, 1312,
        h_dec, enc_Wih + 288, 1024, 1024, 1312,
        h_enc, enc_Whh,       1024, 1024, 1024,
        enc_bih, enc_bhh);
    k_lstm<<<2048, 256, 0, stream>>>(gbuf, h_enc, c_enc);
    // stats = h_enc @ zW^T + zb
    gemm3_kernel<<<dim3(4, 8), 256, 0, stream>>>(stats, 512, 256,
        h_enc, zW, 1024, 1024, 1024,
        nullptr, nullptr, 0, 0, 0,
        nullptr, nullptr, 0, 0, 0,
        zb, nullptr);
    k_z<<<256, 256, 0, stream>>>(stats, eps + (size_t)t * 65536, zbuf, out_mu, out_sg, t);
    // dec LSTM: g = z @ dec_Wih^T + h_dec @ dec_Whh^T + biases
    gemm3_kernel<<<dim3(64, 8), 256, 0, stream>>>(gbuf, 512, 4096,
        zbuf,  dec_Wih,  128,  128,  128,
        h_dec, dec_Whh, 1024, 1024, 1024,
        nullptr, nullptr, 0, 0, 0,
        dec_bih, dec_bhh);
    k_lstm<<<2048, 256, 0, stream>>>(gbuf, h_dec, c_dec);
    // write patch (uses NEW h_dec)
    gemm3_kernel<<<dim3(3, 8), 256, 0, stream>>>(wvec, 512, 144,
        h_dec, wW, 1024, 1024, 1024,
        nullptr, nullptr, 0, 0, 0,
        nullptr, nullptr, 0, 0, 0,
        wb, nullptr);
    k_attn<1><<<512, 256, 0, stream>>>(h_dec, waW, wab, Fx, Fy, gam);
    k_write<<<512, 256, 0, stream>>>(c, wvec, Fx, Fy, gam);
  }
}

// Round 5
// 10135.295 us; speedup vs baseline: 1.8901x; 1.8901x over previous
//
#include <hip/hip_runtime.h>
#include <cstdint>
#include <cstddef>

#define BB 512
#define TT 32
#define LL 1024
#define ZZ 128

typedef unsigned short ushort_t;
typedef __attribute__((ext_vector_type(8))) short s8v;    // 8 bf16 (4 VGPRs)
typedef __attribute__((ext_vector_type(4))) float f32x4;

// ---------------- math helpers ----------------
__device__ __forceinline__ float sigf(float x) { return 1.0f / (1.0f + expf(-x)); }

__device__ __forceinline__ ushort_t f2bf(float f) {
  uint32_t u = __float_as_uint(f);
  uint32_t r = (u + 0x7FFFu + ((u >> 16) & 1u)) >> 16;   // RNE
  return (ushort_t)r;
}
__device__ __forceinline__ float bf2f(ushort_t h) {
  return __uint_as_float(((uint32_t)h) << 16);
}
__device__ __forceinline__ void splitf(float v, ushort_t& hi, ushort_t& lo) {
  hi = f2bf(v);
  lo = f2bf(v - bf2f(hi));
}

// XLA ErfInv32 (Giles polynomial)
__device__ __forceinline__ float jax_erfinv(float x) {
  float w = -log1pf(-x * x);
  float p;
  if (w < 5.0f) {
    w = w - 2.5f;
    p = 2.81022636e-08f;
    p = fmaf(p, w, 3.43273939e-07f);
    p = fmaf(p, w, -3.5233877e-06f);
    p = fmaf(p, w, -4.39150654e-06f);
    p = fmaf(p, w, 0.00021858087f);
    p = fmaf(p, w, -0.00125372503f);
    p = fmaf(p, w, -0.00417768164f);
    p = fmaf(p, w, 0.246640727f);
    p = fmaf(p, w, 1.50140941f);
  } else {
    w = sqrtf(w) - 3.0f;
    p = -0.000200214257f;
    p = fmaf(p, w, 0.000100950558f);
    p = fmaf(p, w, 0.00134934322f);
    p = fmaf(p, w, -0.00367342844f);
    p = fmaf(p, w, 0.00573950773f);
    p = fmaf(p, w, -0.0076224613f);
    p = fmaf(p, w, 0.00943887047f);
    p = fmaf(p, w, 1.00167406f);
    p = fmaf(p, w, 2.83297682f);
  }
  return p * x;
}

// Threefry-2x32, 20 rounds (JAX schedule)
__device__ __forceinline__ void threefry(uint32_t k0, uint32_t k1,
                                         uint32_t x0, uint32_t x1,
                                         uint32_t& o0, uint32_t& o1) {
  uint32_t ks0 = k0, ks1 = k1, ks2 = k0 ^ k1 ^ 0x1BD11BDAu;
  x0 += ks0; x1 += ks1;
#define TF_ROT(x, d) (((x) << (d)) | ((x) >> (32 - (d))))
#define TF_RND(r) { x0 += x1; x1 = TF_ROT(x1, r); x1 ^= x0; }
  TF_RND(13) TF_RND(15) TF_RND(26) TF_RND(6)
  x0 += ks1; x1 += ks2 + 1u;
  TF_RND(17) TF_RND(29) TF_RND(16) TF_RND(24)
  x0 += ks2; x1 += ks0 + 2u;
  TF_RND(13) TF_RND(15) TF_RND(26) TF_RND(6)
  x0 += ks0; x1 += ks1 + 3u;
  TF_RND(17) TF_RND(29) TF_RND(16) TF_RND(24)
  x0 += ks1; x1 += ks2 + 4u;
  TF_RND(13) TF_RND(15) TF_RND(26) TF_RND(6)
  x0 += ks2; x1 += ks0 + 5u;
#undef TF_RND
#undef TF_ROT
  o0 = x0; o1 = x1;
}

__device__ __forceinline__ float bits_to_normal(uint32_t bits) {
  uint32_t fb = (bits >> 9) | 0x3f800000u;
  float f = __uint_as_float(fb) - 1.0f;
  const float lo = -0.99999994f;
  float u = fmaxf(lo, f * 2.0f + lo);
  return 1.41421356237f * jax_erfinv(u);
}

// ---------------- weight split: f32 -> bf16 hi/lo ----------------
__global__ __launch_bounds__(256) void k_split(const float* __restrict__ src,
                                               ushort_t* __restrict__ hi,
                                               ushort_t* __restrict__ lo, int n) {
  int i = blockIdx.x * 256 + threadIdx.x;
  if (i >= n) return;
  ushort_t h, l;
  splitf(src[i], h, l);
  hi[i] = h; lo[i] = l;
}

// ---------------- MFMA GEMM: C[512][N] = sum_seg A_s @ W_s^T + b0 + b1 ----------------
struct Seg { const ushort_t* A; const ushort_t* W; int K; int lda; int ldw; };
struct SegList { Seg s[9]; int n; };

__device__ __forceinline__ void load_tile(const Seg& sg, int bm, int bn, int N, int k0,
                                          int row, int part, s8v& va, s8v& vw) {
  va = *(const s8v*)(sg.A + (size_t)(bm + row) * sg.lda + k0 + part * 8);
  int n = bn + row;
  if (n < N) vw = *(const s8v*)(sg.W + (size_t)n * sg.ldw + k0 + part * 8);
  else       vw = (s8v)(short)0;
}

__global__ __launch_bounds__(256) void mfma_gemm(
    float* __restrict__ C, int N, SegList segs,
    const float* __restrict__ b0, const float* __restrict__ b1) {
  __shared__ __align__(16) ushort_t As[64][40];   // BK=32, pad to 40 (2-way free)
  __shared__ __align__(16) ushort_t Ws[64][40];
  const int bm = blockIdx.y * 64, bn = blockIdx.x * 64;
  const int tid = threadIdx.x;
  const int w = tid >> 6, lane = tid & 63;
  const int wr = w >> 1, wc = w & 1;              // 2x2 wave grid, 32x32/wave
  const int lr = lane & 15, lq = lane >> 4;
  const int srow = tid >> 2, spart = tid & 3;     // staging: 64 rows x 4x(8 bf16)
  f32x4 acc[2][2] = {};

  int si = 0, k0 = 0;
  s8v va, vw;
  load_tile(segs.s[0], bm, bn, N, 0, srow, spart, va, vw);
  while (1) {
    __syncthreads();
    *(s8v*)&As[srow][spart * 8] = va;
    *(s8v*)&Ws[srow][spart * 8] = vw;
    __syncthreads();
    int nsi = si, nk0 = k0 + 32;
    if (nk0 >= segs.s[si].K) { nk0 = 0; nsi = si + 1; }
    const bool more = (nsi < segs.n);
    if (more) load_tile(segs.s[nsi], bm, bn, N, nk0, srow, spart, va, vw);
    s8v af0 = *(const s8v*)&As[wr * 32 + lr][lq * 8];
    s8v af1 = *(const s8v*)&As[wr * 32 + 16 + lr][lq * 8];
    s8v bf0 = *(const s8v*)&Ws[wc * 32 + lr][lq * 8];
    s8v bf1 = *(const s8v*)&Ws[wc * 32 + 16 + lr][lq * 8];
    acc[0][0] = __builtin_amdgcn_mfma_f32_16x16x32_bf16(af0, bf0, acc[0][0], 0, 0, 0);
    acc[0][1] = __builtin_amdgcn_mfma_f32_16x16x32_bf16(af0, bf1, acc[0][1], 0, 0, 0);
    acc[1][0] = __builtin_amdgcn_mfma_f32_16x16x32_bf16(af1, bf0, acc[1][0], 0, 0, 0);
    acc[1][1] = __builtin_amdgcn_mfma_f32_16x16x32_bf16(af1, bf1, acc[1][1], 0, 0, 0);
    if (!more) break;
    si = nsi; k0 = nk0;
  }
#pragma unroll
  for (int n2 = 0; n2 < 2; ++n2) {
    int col = bn + wc * 32 + n2 * 16 + lr;
    if (col < N) {
      float bias = (b0 ? b0[col] : 0.f) + (b1 ? b1[col] : 0.f);
#pragma unroll
      for (int m = 0; m < 2; ++m)
#pragma unroll
        for (int j = 0; j < 4; ++j) {
          int rr = bm + wr * 32 + m * 16 + lq * 4 + j;   // C/D: col=lane&15, row=(lane>>4)*4+j
          C[(size_t)rr * N + col] = acc[m][n2][j] + bias;
        }
    }
  }
}

// ---------------- fallback f32 GEMM (proven round-3 path) ----------------
__global__ __launch_bounds__(256) void gemm3_kernel(
    float* __restrict__ C, int M, int N,
    const float* __restrict__ A0, const float* __restrict__ W0, int K0, int lda0, int ldw0,
    const float* __restrict__ A1, const float* __restrict__ W1, int K1, int lda1, int ldw1,
    const float* __restrict__ A2, const float* __restrict__ W2, int K2, int lda2, int ldw2,
    const float* __restrict__ b0, const float* __restrict__ b1) {
  __shared__ float Asf[16][68];
  __shared__ float Bsf[16][68];
  const int bm = blockIdx.y * 64, bn = blockIdx.x * 64;
  const int tid = threadIdx.x, tx = tid & 15, ty = tid >> 4;
  float acc[4][4] = {{0.f}};
  const float* Aarr[3] = {A0, A1, A2};
  const float* Warr[3] = {W0, W1, W2};
  const int Karr[3] = {K0, K1, K2};
  const int ldaA[3] = {lda0, lda1, lda2};
  const int ldwA[3] = {ldw0, ldw1, ldw2};
#pragma unroll
  for (int s = 0; s < 3; ++s) {
    const float* A = Aarr[s];
    const float* W = Warr[s];
    const int K = Karr[s], lda = ldaA[s], ldw = ldwA[s];
    if (K == 0) continue;
    for (int k0 = 0; k0 < K; k0 += 16) {
#pragma unroll
      for (int i = 0; i < 4; ++i) {
        int e = tid + 256 * i;
        int row = e >> 4, kk = e & 15;
        Asf[kk][row] = A[(size_t)(bm + row) * lda + k0 + kk];
        int n = bn + row;
        Bsf[kk][row] = (n < N) ? W[(size_t)n * ldw + k0 + kk] : 0.f;
      }
      __syncthreads();
#pragma unroll
      for (int kk = 0; kk < 16; ++kk) {
        float4 av = *reinterpret_cast<const float4*>(&Asf[kk][ty * 4]);
        float4 bv = *reinterpret_cast<const float4*>(&Bsf[kk][tx * 4]);
        const float a4[4] = {av.x, av.y, av.z, av.w};
        const float b4[4] = {bv.x, bv.y, bv.z, bv.w};
#pragma unroll
        for (int i = 0; i < 4; ++i)
#pragma unroll
          for (int j = 0; j < 4; ++j) acc[i][j] = fmaf(a4[i], b4[j], acc[i][j]);
      }
      __syncthreads();
    }
  }
#pragma unroll
  for (int i = 0; i < 4; ++i) {
    int m = bm + ty * 4 + i;
#pragma unroll
    for (int j = 0; j < 4; ++j) {
      int n = bn + tx * 4 + j;
      if (n < N) {
        float v = acc[i][j];
        if (b0) v += b0[n];
        if (b1) v += b1[n];
        C[(size_t)m * N + n] = v;
      }
    }
  }
}

// ---------------- attention params + filterbank ----------------
template <int WRITE>
__global__ __launch_bounds__(256) void k_attn(
    const float* __restrict__ h_dec, const float* __restrict__ aW, const float* __restrict__ ab,
    float* __restrict__ Fx, float* __restrict__ Fy, float* __restrict__ gamma) {
  int b = blockIdx.x;
  __shared__ float a_sh[5];
  __shared__ float fx_sh[12][64], fy_sh[12][64];
  __shared__ float srow_sh[24];
  int tid = threadIdx.x;
  int wave = tid >> 6, lane = tid & 63;
  const float* h = h_dec + (size_t)b * LL;
  for (int o = wave; o < 5; o += 4) {
    float s = 0.f;
    const float* wv = aW + (size_t)o * LL;
    for (int k = lane; k < LL; k += 64) s += h[k] * wv[k];
#pragma unroll
    for (int d = 32; d; d >>= 1) s += __shfl_xor(s, d, 64);
    if (lane == 0) a_sh[o] = s + ab[o];
  }
  __syncthreads();
  float gx = 32.5f * (a_sh[0] + 1.f);
  float gy = 32.5f * (a_sh[1] + 1.f);
  float i2v = 0.5f * expf(-a_sh[2]);
  float delta = (63.f / 11.f) * expf(a_sh[3]);
  if (tid == 0) gamma[b] = WRITE ? expf(-a_sh[4]) : expf(a_sh[4]);
  for (int e = tid; e < 768; e += 256) {
    int n = e >> 6, p = e & 63;
    float mu_x = gx + ((float)n - 5.5f) * delta;
    float mu_y = gy + ((float)n - 5.5f) * delta;
    float dx = (float)(p + 1) - mu_x;
    float dy = (float)(p + 1) - mu_y;
    fx_sh[n][p] = expf(-i2v * dx * dx);
    fy_sh[n][p] = expf(-i2v * dy * dy);
  }
  __syncthreads();
  if (tid < 24) {
    int n = tid % 12;
    float s = 0.f;
    if (tid < 12) { for (int p = 0; p < 64; ++p) s += fx_sh[n][p]; }
    else          { for (int p = 0; p < 64; ++p) s += fy_sh[n][p]; }
    srow_sh[tid] = s + 6.4e-7f;
  }
  __syncthreads();
  for (int e = tid; e < 768; e += 256) {
    int n = e >> 6, p = e & 63;
    Fx[((size_t)b * 12 + n) * 64 + p] = fx_sh[n][p] / srow_sh[n];
    Fy[((size_t)b * 12 + n) * 64 + p] = fy_sh[n][p] / srow_sh[12 + n];
  }
}

// ---------------- read ----------------
__global__ __launch_bounds__(256) void k_read(
    const float* __restrict__ x, const float* __restrict__ c,
    const float* __restrict__ Fx, const float* __restrict__ Fy,
    const float* __restrict__ gamma, float* __restrict__ r,
    ushort_t* __restrict__ rH, ushort_t* __restrict__ rL) {
  int b = blockIdx.x;
  __shared__ float X[64][64];
  __shared__ float Xh[64][64];
  __shared__ float fx[12][64], fy[12][64];
  __shared__ float tmp[12][64], tmph[12][64];
  int tid = threadIdx.x;
  for (int e = tid; e < 4096; e += 256) {
    float xv = x[(size_t)b * 4096 + e];
    float cv = c[(size_t)b * 4096 + e];
    X[e >> 6][e & 63] = xv;
    Xh[e >> 6][e & 63] = xv - sigf(cv);
  }
  for (int e = tid; e < 768; e += 256) {
    fx[e >> 6][e & 63] = Fx[(size_t)b * 768 + e];
    fy[e >> 6][e & 63] = Fy[(size_t)b * 768 + e];
  }
  __syncthreads();
  for (int e = tid; e < 768; e += 256) {
    int n = e >> 6, w2 = e & 63;
    float s = 0.f, sh = 0.f;
    for (int hh = 0; hh < 64; ++hh) {
      float f = fy[n][hh];
      s  = fmaf(f, X[hh][w2], s);
      sh = fmaf(f, Xh[hh][w2], sh);
    }
    tmp[n][w2] = s; tmph[n][w2] = sh;
  }
  __syncthreads();
  float gam = gamma[b];
  if (tid < 144) {
    int n = tid / 12, m = tid % 12;
    float s = 0.f, sh = 0.f;
    for (int w2 = 0; w2 < 64; ++w2) {
      float f = fx[m][w2];
      s  = fmaf(tmp[n][w2], f, s);
      sh = fmaf(tmph[n][w2], f, sh);
    }
    float v0 = gam * s, v1 = gam * sh;
    size_t i0 = (size_t)b * 288 + n * 12 + m;
    size_t i1 = i0 + 144;
    r[i0] = v0; r[i1] = v1;
    ushort_t h0, l0, h1, l1;
    splitf(v0, h0, l0); splitf(v1, h1, l1);
    rH[i0] = h0; rL[i0] = l0;
    rH[i1] = h1; rL[i1] = l1;
  }
}

// ---------------- write ----------------
__global__ __launch_bounds__(256) void k_write(
    float* __restrict__ c, const float* __restrict__ wvec,
    const float* __restrict__ Fx, const float* __restrict__ Fy,
    const float* __restrict__ gamma) {
  int b = blockIdx.x;
  __shared__ float fx[12][64], fy[12][64], wsm[12][12], tmp[12][64];
  int tid = threadIdx.x;
  for (int e = tid; e < 768; e += 256) {
    fx[e >> 6][e & 63] = Fx[(size_t)b * 768 + e];
    fy[e >> 6][e & 63] = Fy[(size_t)b * 768 + e];
  }
  if (tid < 144) wsm[tid / 12][tid % 12] = wvec[(size_t)b * 144 + tid];
  __syncthreads();
  for (int e = tid; e < 768; e += 256) {
    int n = e >> 6, w2 = e & 63;
    float s = 0.f;
#pragma unroll
    for (int m = 0; m < 12; ++m) s = fmaf(wsm[n][m], fx[m][w2], s);
    tmp[n][w2] = s;
  }
  __syncthreads();
  float gam = gamma[b];
  for (int e = tid; e < 4096; e += 256) {
    int hh = e >> 6, w2 = e & 63;
    float s = 0.f;
#pragma unroll
    for (int n = 0; n < 12; ++n) s = fmaf(fy[n][hh], tmp[n][w2], s);
    c[(size_t)b * 4096 + e] += gam * s;
  }
}

// ---------------- LSTM gates (+ bf16 split of h) ----------------
__global__ __launch_bounds__(256) void k_lstm(const float* __restrict__ g,
                                              float* __restrict__ h, float* __restrict__ cst,
                                              ushort_t* __restrict__ hH,
                                              ushort_t* __restrict__ hL) {
  int i = blockIdx.x * 256 + threadIdx.x;
  int b = i >> 10, u = i & 1023;
  const float* gb = g + (size_t)b * 4096;
  float ig = gb[u], fg = gb[1024 + u], gg = gb[2048 + u], og = gb[3072 + u];
  float cv = sigf(fg) * cst[i] + sigf(ig) * tanhf(gg);
  cst[i] = cv;
  float hv = sigf(og) * tanhf(cv);
  h[i] = hv;
  ushort_t hh, hl;
  splitf(hv, hh, hl);
  hH[i] = hh; hL[i] = hl;
}

// ---------------- z = mu + sig*eps (inline threefry RNG) ----------------
__global__ __launch_bounds__(256) void k_z(const float* __restrict__ stats,
                                           float* __restrict__ z,
                                           ushort_t* __restrict__ zH,
                                           ushort_t* __restrict__ zL,
                                           float* __restrict__ out_mu,
                                           float* __restrict__ out_sg, int t) {
  int i = blockIdx.x * 256 + threadIdx.x;  // < 65536
  int b = i >> 7, zi = i & 127;
  uint32_t kA, kB, o0, o1;
  threefry(0u, 42u, 0u, (uint32_t)t, kA, kB);          // split(key(42),32)[t]
  threefry(kA, kB, 0u, (uint32_t)i, o0, o1);           // random_bits
  float ep = bits_to_normal(o0 ^ o1);
  float mu = stats[(size_t)b * 256 + zi];
  float sg = expf(stats[(size_t)b * 256 + 128 + zi]);
  float zv = mu + sg * ep;
  z[i] = zv;
  ushort_t zh, zl;
  splitf(zv, zh, zl);
  zH[i] = zh; zL[i] = zl;
  out_mu[(size_t)b * 4096 + zi * 32 + t] = mu;
  out_sg[(size_t)b * 4096 + zi * 32 + t] = sg;
}

// ---------------- host launch ----------------
extern "C" void kernel_launch(void* const* d_in, const int* in_sizes, int n_in,
                              void* d_out, int out_size, void* d_ws, size_t ws_size,
                              hipStream_t stream) {
  const float* x       = (const float*)d_in[0];
  const float* enc_Wih = (const float*)d_in[1];
  const float* enc_Whh = (const float*)d_in[2];
  const float* enc_bih = (const float*)d_in[3];
  const float* enc_bhh = (const float*)d_in[4];
  const float* dec_Wih = (const float*)d_in[5];
  const float* dec_Whh = (const float*)d_in[6];
  const float* dec_bih = (const float*)d_in[7];
  const float* dec_bhh = (const float*)d_in[8];
  const float* zW  = (const float*)d_in[9];
  const float* zb  = (const float*)d_in[10];
  const float* wW  = (const float*)d_in[11];
  const float* wb  = (const float*)d_in[12];
  const float* raW = (const float*)d_in[13];
  const float* rab = (const float*)d_in[14];
  const float* waW = (const float*)d_in[15];
  const float* wab = (const float*)d_in[16];

  float* out = (float*)d_out;
  float* c      = out;
  float* out_mu = out + 2097152;
  float* out_sg = out + 4194304;

  // ---- workspace layout (bytes, 256-aligned) ----
  char* base = (char*)d_ws;
  size_t off = 0;
  auto alloc = [&](size_t bytes) -> char* {
    char* p = base + off;
    off = (off + bytes + 255) & ~(size_t)255;
    return p;
  };
  // zero-block: states + recurrent bf16 splits (must be contiguous & first)
  float* h_enc = (float*)alloc(2097152);
  float* c_enc = (float*)alloc(2097152);
  float* h_dec = (float*)alloc(2097152);
  float* c_dec = (float*)alloc(2097152);
  ushort_t* hdH = (ushort_t*)alloc(1048576);
  ushort_t* hdL = (ushort_t*)alloc(1048576);
  ushort_t* heH = (ushort_t*)alloc(1048576);
  ushort_t* heL = (ushort_t*)alloc(1048576);
  size_t zero_bytes = off;
  // per-step buffers
  ushort_t* rH = (ushort_t*)alloc(294912);
  ushort_t* rL = (ushort_t*)alloc(294912);
  ushort_t* zH = (ushort_t*)alloc(131072);
  ushort_t* zL = (ushort_t*)alloc(131072);
  float* gbuf  = (float*)alloc(8388608);
  float* stats = (float*)alloc(524288);
  float* rbuf  = (float*)alloc(589824);
  float* zbuf  = (float*)alloc(262144);
  float* Fx    = (float*)alloc(1572864);
  float* Fy    = (float*)alloc(1572864);
  float* gam   = (float*)alloc(2048);
  float* wvec  = (float*)alloc(294912);
  // weight splits (bf16 hi/lo)
  ushort_t* eWihH = (ushort_t*)alloc(10747904);
  ushort_t* eWihL = (ushort_t*)alloc(10747904);
  ushort_t* eWhhH = (ushort_t*)alloc(8388608);
  ushort_t* eWhhL = (ushort_t*)alloc(8388608);
  ushort_t* dWihH = (ushort_t*)alloc(1048576);
  ushort_t* dWihL = (ushort_t*)alloc(1048576);
  ushort_t* dWhhH = (ushort_t*)alloc(8388608);
  ushort_t* dWhhL = (ushort_t*)alloc(8388608);
  ushort_t* zWH   = (ushort_t*)alloc(524288);
  ushort_t* zWL   = (ushort_t*)alloc(524288);
  ushort_t* wWH   = (ushort_t*)alloc(294912);
  ushort_t* wWL   = (ushort_t*)alloc(294912);
  const size_t need = off;
  const bool fast = (ws_size >= need);

  hipMemsetAsync(c, 0, (size_t)2097152 * sizeof(float), stream);
  hipMemsetAsync(base, 0, zero_bytes, stream);

  SegList encS, decS, staS, wvS;
  if (fast) {
    // split weights once per launch
    k_split<<<(5373952 + 255) / 256, 256, 0, stream>>>(enc_Wih, eWihH, eWihL, 5373952);
    k_split<<<(4194304 + 255) / 256, 256, 0, stream>>>(enc_Whh, eWhhH, eWhhL, 4194304);
    k_split<<<(524288 + 255) / 256, 256, 0, stream>>>(dec_Wih, dWihH, dWihL, 524288);
    k_split<<<(4194304 + 255) / 256, 256, 0, stream>>>(dec_Whh, dWhhH, dWhhL, 4194304);
    k_split<<<(262144 + 255) / 256, 256, 0, stream>>>(zW, zWH, zWL, 262144);
    k_split<<<(147456 + 255) / 256, 256, 0, stream>>>(wW, wWH, wWL, 147456);

    encS.n = 9;
    encS.s[0] = {rH,  eWihH,       288, 288, 1312};
    encS.s[1] = {rL,  eWihH,       288, 288, 1312};
    encS.s[2] = {rH,  eWihL,       288, 288, 1312};
    encS.s[3] = {hdH, eWihH + 288, 1024, 1024, 1312};
    encS.s[4] = {hdL, eWihH + 288, 1024, 1024, 1312};
    encS.s[5] = {hdH, eWihL + 288, 1024, 1024, 1312};
    encS.s[6] = {heH, eWhhH,       1024, 1024, 1024};
    encS.s[7] = {heL, eWhhH,       1024, 1024, 1024};
    encS.s[8] = {heH, eWhhL,       1024, 1024, 1024};
    decS.n = 6;
    decS.s[0] = {zH,  dWihH, 128, 128, 128};
    decS.s[1] = {zL,  dWihH, 128, 128, 128};
    decS.s[2] = {zH,  dWihL, 128, 128, 128};
    decS.s[3] = {hdH, dWhhH, 1024, 1024, 1024};
    decS.s[4] = {hdL, dWhhH, 1024, 1024, 1024};
    decS.s[5] = {hdH, dWhhL, 1024, 1024, 1024};
    staS.n = 3;
    staS.s[0] = {heH, zWH, 1024, 1024, 1024};
    staS.s[1] = {heL, zWH, 1024, 1024, 1024};
    staS.s[2] = {heH, zWL, 1024, 1024, 1024};
    wvS.n = 3;
    wvS.s[0] = {hdH, wWH, 1024, 1024, 1024};
    wvS.s[1] = {hdL, wWH, 1024, 1024, 1024};
    wvS.s[2] = {hdH, wWL, 1024, 1024, 1024};
  }

  for (int t = 0; t < TT; ++t) {
    k_attn<0><<<512, 256, 0, stream>>>(h_dec, raW, rab, Fx, Fy, gam);
    k_read<<<512, 256, 0, stream>>>(x, c, Fx, Fy, gam, rbuf, rH, rL);
    if (fast) {
      mfma_gemm<<<dim3(64, 8), 256, 0, stream>>>(gbuf, 4096, encS, enc_bih, enc_bhh);
    } else {
      gemm3_kernel<<<dim3(64, 8), 256, 0, stream>>>(gbuf, 512, 4096,
          rbuf,  enc_Wih,        288, 288, 1312,
          h_dec, enc_Wih + 288, 1024, 1024, 1312,
          h_enc, enc_Whh,       1024, 1024, 1024,
          enc_bih, enc_bhh);
    }
    k_lstm<<<2048, 256, 0, stream>>>(gbuf, h_enc, c_enc, heH, heL);
    if (fast) {
      mfma_gemm<<<dim3(4, 8), 256, 0, stream>>>(stats, 256, staS, zb, nullptr);
    } else {
      gemm3_kernel<<<dim3(4, 8), 256, 0, stream>>>(stats, 512, 256,
          h_enc, zW, 1024, 1024, 1024,
          nullptr, nullptr, 0, 0, 0,
          nullptr, nullptr, 0, 0, 0,
          zb, nullptr);
    }
    k_z<<<256, 256, 0, stream>>>(stats, zbuf, zH, zL, out_mu, out_sg, t);
    if (fast) {
      mfma_gemm<<<dim3(64, 8), 256, 0, stream>>>(gbuf, 4096, decS, dec_bih, dec_bhh);
    } else {
      gemm3_kernel<<<dim3(64, 8), 256, 0, stream>>>(gbuf, 512, 4096,
          zbuf,  dec_Wih,  128,  128,  128,
          h_dec, dec_Whh, 1024, 1024, 1024,
          nullptr, nullptr, 0, 0, 0,
          dec_bih, dec_bhh);
    }
    k_lstm<<<2048, 256, 0, stream>>>(gbuf, h_dec, c_dec, hdH, hdL);
    if (fast) {
      mfma_gemm<<<dim3(3, 8), 256, 0, stream>>>(wvec, 144, wvS, wb, nullptr);
    } else {
      gemm3_kernel<<<dim3(3, 8), 256, 0, stream>>>(wvec, 512, 144,
          h_dec, wW, 1024, 1024, 1024,
          nullptr, nullptr, 0, 0, 0,
          nullptr, nullptr, 0, 0, 0,
          wb, nullptr);
    }
    k_attn<1><<<512, 256, 0, stream>>>(h_dec, waW, wab, Fx, Fy, gam);
    k_write<<<512, 256, 0, stream>>>(c, wvec, Fx, Fy, gam);
  }
}